// Round 5
// baseline (33.222 us; speedup 1.0000x reference)
//
#include <hip/hip_runtime.h>
#include <hip/hip_fp16.h>

#define N 2048
#define IN_DIM 128
#define D 64
#define ALPHA 0.2f
#define TI 8
#define BLK 1024
#define NW (BLK / 64)   // 16 waves per block

// e[i,j] = b_i + b_j + sum_d 0.4*a_d*|Wh[i,d]+Wh[j,d]|,  b_i = 0.6*dot(a,Wh_i)
// Softmax invariances: b_i dropped (per-row constant), p scaled by 2^-6.
// bs2[j] = 0.6*dot(a,Wh_j)*log2(e) - 6 precomputed -> phase 2 is fma+exp2.
// TI=8/BLK=1024: 256 blocks; each block streams WhP+WhQ once -> grid-wide
// L2 stream traffic halves vs TI=4 (128 MB total). Occupancy unchanged
// (16 waves/CU = 4/SIMD). Per-thread VALU unchanged (2 j's x 8 rows).

typedef _Float16 half2v __attribute__((ext_vector_type(2)));

__device__ __forceinline__ unsigned short f2h_rne(float f) {
  return __half_as_ushort(__float2half(f));
}

__device__ __forceinline__ float dot2abs(unsigned s2, unsigned w2,
                                         unsigned a2, float acc) {
  half2v sv = __builtin_bit_cast(half2v, s2);
  half2v wv = __builtin_bit_cast(half2v, w2);
  half2v t = sv + wv;                                   // v_pk_add_f16
  unsigned tu = __builtin_bit_cast(unsigned, t) & 0x7fff7fffu;  // packed abs
  return __builtin_amdgcn_fdot2(__builtin_bit_cast(half2v, tu),
                                __builtin_bit_cast(half2v, a2),
                                acc, false);            // v_dot2_f32_f16
}

__device__ __forceinline__ float dot2u(unsigned p2, unsigned w2, float acc) {
  return __builtin_amdgcn_fdot2(__builtin_bit_cast(half2v, p2),
                                __builtin_bit_cast(half2v, w2),
                                acc, false);            // v_dot2_f32_f16
}

__device__ __forceinline__ unsigned cvt_pk_u(float lo, float hi) {
  return __builtin_bit_cast(unsigned, __builtin_amdgcn_cvt_pkrtz(lo, hi));
}

// Kernel 1: Whh f16 [N,D], WhP u32 [D/2][N] packed f16 d-pairs transposed,
// WhQ u32 [N/2][D] packed f16 row-pairs, bs2[j] = 0.6*dot(a,Wh_j)*L2E - 6,
// ap2 = packed f16 pairs of 0.4*a
__global__ __launch_bounds__(256) void wh_kernel(
    const float* __restrict__ H, const float* __restrict__ W,
    const float* __restrict__ a, unsigned short* __restrict__ Whh,
    unsigned int* __restrict__ WhP, unsigned int* __restrict__ WhQ,
    float* __restrict__ bs2, unsigned int* __restrict__ ap2) {
  __shared__ float wlds[D][IN_DIM + 1];
  __shared__ float hl[8 * IN_DIM];
  const int t = threadIdx.x;
  const int i0 = blockIdx.x * 8;

  if (blockIdx.x == 0 && t < D / 2) {
    ap2[t] = (unsigned)f2h_rne(0.4f * a[2 * t]) |
             ((unsigned)f2h_rne(0.4f * a[2 * t + 1]) << 16);
  }

  #pragma unroll
  for (int rep = 0; rep < 8; ++rep) {
    int idx = rep * 1024 + t * 4;
    float4 w4 = *(const float4*)&W[idx];
    int d = idx / IN_DIM, k = idx % IN_DIM;
    wlds[d][k] = w4.x; wlds[d][k + 1] = w4.y;
    wlds[d][k + 2] = w4.z; wlds[d][k + 3] = w4.w;
  }
  *(float4*)&hl[t * 4] = *(const float4*)&H[i0 * IN_DIM + t * 4];
  __syncthreads();

  const int wid = t >> 6, lane = t & 63;
  const float av = a[lane];
  const int lr0 = wid * 2, lr1 = lr0 + 1;
  const int ia = i0 + lr0, ib = i0 + lr1;

  float acc0 = 0.f, acc1 = 0.f;
  #pragma unroll 4
  for (int k = 0; k < IN_DIM; ++k) {
    float wv = wlds[lane][k];
    acc0 = fmaf(hl[lr0 * IN_DIM + k], wv, acc0);
    acc1 = fmaf(hl[lr1 * IN_DIM + k], wv, acc1);
  }

  unsigned h0 = f2h_rne(acc0), h1 = f2h_rne(acc1);
  Whh[ia * D + lane] = (unsigned short)h0;
  Whh[ib * D + lane] = (unsigned short)h1;
  unsigned q0 = (unsigned)__shfl_xor((int)h0, 1);
  unsigned q1 = (unsigned)__shfl_xor((int)h1, 1);
  if (!(lane & 1)) {
    WhP[(lane >> 1) * N + ia] = h0 | (q0 << 16);
    WhP[(lane >> 1) * N + ib] = h1 | (q1 << 16);
  }
  // row-pair pack: lo = even row (ia), hi = odd row (ib)
  WhQ[(blockIdx.x * 4 + wid) * D + lane] = h0 | (h1 << 16);

  float pb0 = av * acc0, pb1 = av * acc1;
  #pragma unroll
  for (int off = 32; off; off >>= 1) {
    pb0 += __shfl_xor(pb0, off);
    pb1 += __shfl_xor(pb1, off);
  }
  const float L2E = 1.4426950408889634f;
  if (lane == 0) {
    bs2[ia] = fmaf(0.6f * pb0, L2E, -6.f);
    bs2[ib] = fmaf(0.6f * pb1, L2E, -6.f);
  }
}

// Kernel 2: fused e -> exp -> sum -> PV. 1024 threads, TI=8 rows, 2 j/thread.
__global__ __launch_bounds__(BLK, 4) void attn_kernel(
    const unsigned short* __restrict__ Whh,
    const unsigned int* __restrict__ WhP,
    const unsigned int* __restrict__ WhQ,
    const float* __restrict__ bs2, const unsigned int* __restrict__ ap2,
    float* __restrict__ out) {
  __shared__ unsigned short p_lds[TI][N];  // 32 KB, f16 (scaled by 2^-6)
  __shared__ float red2s[TI][NW];          // 512 B
  __shared__ float part[NW][TI][D];        // 32 KB
  __shared__ uint4 stage[TI * 8 + D / 8];  // 1152 B: Whh rows + ap2

  const int t = threadIdx.x;
  const int i0 = blockIdx.x * TI;
  const int wid = t >> 6, lane = t & 63;

  // Stage block-uniform operands once
  if (t < TI * 8 + D / 8) {
    stage[t] = (t < TI * 8) ? ((const uint4*)(Whh + i0 * D))[t]
                            : ((const uint4*)ap2)[t - TI * 8];
  }
  __syncthreads();

  // ---- Phase 1: e row-block (1024 thr x 2 j), packed-f16 dot2 core ----
  const int j0 = t * 2;
  float2 bj = *(const float2*)&bs2[j0];
  float2 ac[TI];
  #pragma unroll
  for (int ti = 0; ti < TI; ++ti) { ac[ti].x = ac[ti].y = 0.f; }

  const unsigned int* wp = WhP + j0;      // column pair stream, stride N

  uint2 wbuf[2][4];
  #pragma unroll
  for (int q = 0; q < 4; ++q) wbuf[0][q] = *(const uint2*)&wp[q * N];

  #pragma unroll
  for (int c = 0; c < D / 8; ++c) {       // 8 chunks of 4 d-pairs (8 d's)
    const int cur = c & 1, nxt = cur ^ 1;
    if (c < D / 8 - 1) {
      #pragma unroll
      for (int q = 0; q < 4; ++q)
        wbuf[nxt][q] = *(const uint2*)&wp[((c + 1) * 4 + q) * N];
    }
    const uint4 a4 = stage[TI * 8 + c];   // LDS broadcast
    uint4 s4l[TI];
    #pragma unroll
    for (int ti = 0; ti < TI; ++ti) s4l[ti] = stage[ti * 8 + c];
    #pragma unroll
    for (int q = 0; q < 4; ++q) {
      const unsigned a2 = (q == 0) ? a4.x : (q == 1) ? a4.y
                        : (q == 2) ? a4.z : a4.w;
      const uint2 w2 = wbuf[cur][q];
      #pragma unroll
      for (int ti = 0; ti < TI; ++ti) {
        const unsigned s2 = (q == 0) ? s4l[ti].x : (q == 1) ? s4l[ti].y
                          : (q == 2) ? s4l[ti].z : s4l[ti].w;
        ac[ti].x = dot2abs(s2, w2.x, a2, ac[ti].x);
        ac[ti].y = dot2abs(s2, w2.y, a2, ac[ti].y);
      }
    }
  }

  // ---- Phase 2: p = exp2(ac*L2E + bs2_j); store packed f16 pairs ----
  const float L2E = 1.4426950408889634f;
  float s_t[TI];
  #pragma unroll
  for (int ti = 0; ti < TI; ++ti) {
    float px = __builtin_amdgcn_exp2f(fmaf(ac[ti].x, L2E, bj.x));
    float py = __builtin_amdgcn_exp2f(fmaf(ac[ti].y, L2E, bj.y));
    *(unsigned*)&p_lds[ti][j0] = cvt_pk_u(px, py);
    s_t[ti] = px + py;
  }
  #pragma unroll
  for (int off = 32; off; off >>= 1) {
    #pragma unroll
    for (int ti = 0; ti < TI; ++ti)
      s_t[ti] += __shfl_xor(s_t[ti], off);
  }
  if (lane == 0) {
    #pragma unroll
    for (int ti = 0; ti < TI; ++ti) red2s[ti][wid] = s_t[ti];
  }
  __syncthreads();   // publishes p_lds + red2s

  // ---- Phase 3: out = (p @ Wh) / rowsum; all-f16 dot2 core ----
  const int jbase = wid * (N / NW);       // 128 rows per wave
  const int hi4 = (lane >> 4) * 4;        // even: row-pairs align
  const int col = (lane & 15) * 4;
  float4 acc[TI];
  #pragma unroll
  for (int ti = 0; ti < TI; ++ti) { acc[ti].x = acc[ti].y = acc[ti].z = acc[ti].w = 0.f; }

  uint4 wq[2][2];
  uint2 pt[2][TI];
  {
    const int r0 = jbase + hi4;
    wq[0][0] = *(const uint4*)&WhQ[(r0 >> 1) * D + col];
    wq[0][1] = *(const uint4*)&WhQ[((r0 >> 1) + 1) * D + col];
    #pragma unroll
    for (int ti = 0; ti < TI; ++ti)
      pt[0][ti] = *(const uint2*)&p_lds[ti][r0];
  }

  #pragma unroll
  for (int it = 0; it < (N / NW) / 16; ++it) {   // 8 iterations
    const int cur = it & 1, nxt = cur ^ 1;
    if (it < (N / NW) / 16 - 1) {
      const int r1 = jbase + (it + 1) * 16 + hi4;
      wq[nxt][0] = *(const uint4*)&WhQ[(r1 >> 1) * D + col];
      wq[nxt][1] = *(const uint4*)&WhQ[((r1 >> 1) + 1) * D + col];
      #pragma unroll
      for (int ti = 0; ti < TI; ++ti)
        pt[nxt][ti] = *(const uint2*)&p_lds[ti][r1];
    }
    #pragma unroll
    for (int ti = 0; ti < TI; ++ti) {
      const unsigned ppA = pt[cur][ti].x;  // (p[r0], p[r0+1])
      const unsigned ppB = pt[cur][ti].y;  // (p[r0+2], p[r0+3])
      acc[ti].x = dot2u(ppB, wq[cur][1].x, dot2u(ppA, wq[cur][0].x, acc[ti].x));
      acc[ti].y = dot2u(ppB, wq[cur][1].y, dot2u(ppA, wq[cur][0].y, acc[ti].y));
      acc[ti].z = dot2u(ppB, wq[cur][1].z, dot2u(ppA, wq[cur][0].z, acc[ti].z));
      acc[ti].w = dot2u(ppB, wq[cur][1].w, dot2u(ppA, wq[cur][0].w, acc[ti].w));
    }
  }
  #pragma unroll
  for (int ti = 0; ti < TI; ++ti) {
    acc[ti].x += __shfl_xor(acc[ti].x, 16);
    acc[ti].y += __shfl_xor(acc[ti].y, 16);
    acc[ti].z += __shfl_xor(acc[ti].z, 16);
    acc[ti].w += __shfl_xor(acc[ti].w, 16);
    acc[ti].x += __shfl_xor(acc[ti].x, 32);
    acc[ti].y += __shfl_xor(acc[ti].y, 32);
    acc[ti].z += __shfl_xor(acc[ti].z, 32);
    acc[ti].w += __shfl_xor(acc[ti].w, 32);
  }
  if (lane < 16) {
    #pragma unroll
    for (int ti = 0; ti < TI; ++ti)
      *(float4*)&part[wid][ti][lane * 4] = acc[ti];
  }
  __syncthreads();
  if (t < TI * D) {
    const int ti = t >> 6, dd = t & 63;
    float s = 0.f;
    #pragma unroll
    for (int w = 0; w < NW; ++w) s += part[w][ti][dd];
    float rsum = 0.f;
    #pragma unroll
    for (int w = 0; w < NW; w += 4) {
      float4 r = *(const float4*)&red2s[ti][w];
      rsum += ((r.x + r.y) + (r.z + r.w));
    }
    out[(i0 + ti) * D + dd] = s * (1.f / rsum);
  }
}

extern "C" void kernel_launch(void* const* d_in, const int* in_sizes, int n_in,
                              void* d_out, int out_size, void* d_ws, size_t ws_size,
                              hipStream_t stream) {
  const float* H = (const float*)d_in[0];
  const float* W = (const float*)d_in[1];
  const float* a = (const float*)d_in[2];
  float* out = (float*)d_out;

  unsigned short* Whh = (unsigned short*)d_ws;          // N*D f16
  unsigned int* WhP = (unsigned int*)(Whh + N * D);     // (D/2)*N u32 f16 d-pairs
  unsigned int* WhQ = WhP + (D / 2) * N;                // (N/2)*D u32 f16 row-pairs
  float* bs2 = (float*)(WhQ + (N / 2) * D);             // N (log2-domain bias)
  unsigned int* ap2 = (unsigned int*)(bs2 + N);         // D/2

  wh_kernel<<<N / 8, 256, 0, stream>>>(H, W, a, Whh, WhP, WhQ, bs2, ap2);
  attn_kernel<<<N / TI, BLK, 0, stream>>>(Whh, WhP, WhQ, bs2, ap2, out);
}